// Round 1
// baseline (425.542 us; speedup 1.0000x reference)
//
#include <hip/hip_runtime.h>
#include <math.h>

#define N_NODES 50000
#define E_EDGES 800000
#define ET      (E_EDGES + N_NODES)   // edges + self loops
#define IN_DIM  128
#define HID     128
#define HEADS   8
#define C1      16
#define OUT_DIM 64
#define NEG_SLOPE 0.2f

#define SCAN_BLOCKS ((N_NODES + 255) / 256)   // 196

// ---------------- CSR build ----------------

__global__ void hist_kernel(const int* __restrict__ dst, int* __restrict__ deg) {
    int i = blockIdx.x * blockDim.x + threadIdx.x;
    if (i < ET) {
        int d = (i < E_EDGES) ? dst[i] : (i - E_EDGES);
        atomicAdd(&deg[d], 1);
    }
}

__global__ void scan_block_kernel(const int* __restrict__ deg, int* __restrict__ excl,
                                  int* __restrict__ blockSums) {
    __shared__ int s[256];
    int t = threadIdx.x;
    int i = blockIdx.x * 256 + t;
    int v = (i < N_NODES) ? deg[i] : 0;
    s[t] = v;
    __syncthreads();
    #pragma unroll
    for (int off = 1; off < 256; off <<= 1) {
        int add = (t >= off) ? s[t - off] : 0;
        __syncthreads();
        s[t] += add;
        __syncthreads();
    }
    if (i < N_NODES) excl[i] = s[t] - v;
    if (t == 255) blockSums[blockIdx.x] = s[255];
}

__global__ void scan_sums_kernel(int* __restrict__ blockSums) {
    __shared__ int s[256];
    int t = threadIdx.x;
    int v = (t < SCAN_BLOCKS) ? blockSums[t] : 0;
    s[t] = v;
    __syncthreads();
    #pragma unroll
    for (int off = 1; off < 256; off <<= 1) {
        int add = (t >= off) ? s[t - off] : 0;
        __syncthreads();
        s[t] += add;
        __syncthreads();
    }
    if (t < SCAN_BLOCKS) blockSums[t] = s[t] - v;   // exclusive
}

__global__ void scan_add_kernel(const int* __restrict__ excl, const int* __restrict__ blockSums,
                                int* __restrict__ row_start, int* __restrict__ cursor) {
    int i = blockIdx.x * 256 + threadIdx.x;
    if (i < N_NODES) {
        int v = excl[i] + blockSums[blockIdx.x];
        row_start[i] = v;
        cursor[i] = v;
    }
    if (i == 0) row_start[N_NODES] = ET;   // total is static
}

__global__ void fill_kernel(const int* __restrict__ src, const int* __restrict__ dst,
                            int* __restrict__ cursor, int* __restrict__ csr_src) {
    int i = blockIdx.x * blockDim.x + threadIdx.x;
    if (i < ET) {
        int s, d;
        if (i < E_EDGES) { s = src[i]; d = dst[i]; }
        else             { s = d = i - E_EDGES; }
        int pos = atomicAdd(&cursor[d], 1);
        csr_src[pos] = s;
    }
}

// ---------------- Layer 1: transform (x@W1, attention dots) ----------------
// 8 nodes per 256-thread block; thread t handles channel c=t&127 for 4 nodes (group t>>7)

__global__ __launch_bounds__(256) void l1_transform(
        const float* __restrict__ x, const float* __restrict__ W1,
        const float* __restrict__ as1, const float* __restrict__ ad1,
        float* __restrict__ h1, float* __restrict__ a_src, float* __restrict__ a_dst) {
    int n0 = blockIdx.x * 8;
    int t = threadIdx.x;
    int c = t & 127;
    int g = t >> 7;          // 0..1 -> nodes g*4 .. g*4+3
    __shared__ float xs[8][IN_DIM];
    for (int i = t; i < 8 * IN_DIM; i += 256) {
        xs[i >> 7][i & 127] = x[(size_t)(n0 + (i >> 7)) * IN_DIM + (i & 127)];
    }
    __syncthreads();
    int nb = g * 4;
    float acc0 = 0.f, acc1 = 0.f, acc2 = 0.f, acc3 = 0.f;
    #pragma unroll 8
    for (int k = 0; k < IN_DIM; ++k) {
        float w = W1[k * HID + c];
        acc0 = fmaf(xs[nb + 0][k], w, acc0);
        acc1 = fmaf(xs[nb + 1][k], w, acc1);
        acc2 = fmaf(xs[nb + 2][k], w, acc2);
        acc3 = fmaf(xs[nb + 3][k], w, acc3);
    }
    h1[(size_t)(n0 + nb + 0) * HID + c] = acc0;
    h1[(size_t)(n0 + nb + 1) * HID + c] = acc1;
    h1[(size_t)(n0 + nb + 2) * HID + c] = acc2;
    h1[(size_t)(n0 + nb + 3) * HID + c] = acc3;

    int h = c >> 4;
    float ws = as1[c], wd = ad1[c];   // att_src1/att_dst1 flat [H*C1] == [128]
    float s0 = acc0 * ws, s1 = acc1 * ws, s2 = acc2 * ws, s3 = acc3 * ws;
    float d0 = acc0 * wd, d1 = acc1 * wd, d2 = acc2 * wd, d3 = acc3 * wd;
    #pragma unroll
    for (int o = 8; o > 0; o >>= 1) {
        s0 += __shfl_down(s0, o, 16); s1 += __shfl_down(s1, o, 16);
        s2 += __shfl_down(s2, o, 16); s3 += __shfl_down(s3, o, 16);
        d0 += __shfl_down(d0, o, 16); d1 += __shfl_down(d1, o, 16);
        d2 += __shfl_down(d2, o, 16); d3 += __shfl_down(d3, o, 16);
    }
    if ((c & 15) == 0) {
        a_src[(n0 + nb + 0) * HEADS + h] = s0;
        a_src[(n0 + nb + 1) * HEADS + h] = s1;
        a_src[(n0 + nb + 2) * HEADS + h] = s2;
        a_src[(n0 + nb + 3) * HEADS + h] = s3;
        a_dst[(n0 + nb + 0) * HEADS + h] = d0;
        a_dst[(n0 + nb + 1) * HEADS + h] = d1;
        a_dst[(n0 + nb + 2) * HEADS + h] = d2;
        a_dst[(n0 + nb + 3) * HEADS + h] = d3;
    }
}

// ---------------- Layer 1: aggregate (online segment softmax) + ELU ----------------

__global__ __launch_bounds__(128) void l1_aggregate(
        const float* __restrict__ h1, const float* __restrict__ a_src,
        const float* __restrict__ a_dst, const int* __restrict__ row_start,
        const int* __restrict__ csr_src, const float* __restrict__ b1,
        float* __restrict__ h_act) {
    int n = blockIdx.x;
    int c = threadIdx.x;
    int h = c >> 4;
    int beg = row_start[n], end = row_start[n + 1];
    float adst = a_dst[n * HEADS + h];
    float m = -INFINITY, l = 0.f, acc = 0.f;
    for (int j = beg; j < end; ++j) {
        int s = csr_src[j];
        float e = a_src[s * HEADS + h] + adst;
        e = e > 0.f ? e : NEG_SLOPE * e;
        float nm = fmaxf(m, e);
        float sc = __expf(m - nm);   // 0 on first iter (m = -inf)
        float p  = __expf(e - nm);
        l = l * sc + p;
        acc = acc * sc + p * h1[(size_t)s * HID + c];
        m = nm;
    }
    float v = acc / (l + 1e-16f) + b1[c];
    v = v > 0.f ? v : (__expf(v) - 1.f);   // ELU
    h_act[(size_t)n * HID + c] = v;
}

// ---------------- Layer 2: transform ----------------
// 8 nodes per 256-thread block; wave g (t>>6) handles nodes g*2, g*2+1, channel c=t&63

__global__ __launch_bounds__(256) void l2_transform(
        const float* __restrict__ h_act, const float* __restrict__ W2,
        const float* __restrict__ as2, const float* __restrict__ ad2,
        float* __restrict__ h2, float* __restrict__ a_src2, float* __restrict__ a_dst2) {
    int n0 = blockIdx.x * 8;
    int t = threadIdx.x;
    int c = t & 63;
    int g = t >> 6;          // 0..3 -> nodes g*2, g*2+1
    __shared__ float hs[8][HID];
    for (int i = t; i < 8 * HID; i += 256) {
        hs[i >> 7][i & 127] = h_act[(size_t)(n0 + (i >> 7)) * HID + (i & 127)];
    }
    __syncthreads();
    int nb = g * 2;
    float acc0 = 0.f, acc1 = 0.f;
    #pragma unroll 8
    for (int k = 0; k < HID; ++k) {
        float w = W2[k * OUT_DIM + c];
        acc0 = fmaf(hs[nb + 0][k], w, acc0);
        acc1 = fmaf(hs[nb + 1][k], w, acc1);
    }
    h2[(size_t)(n0 + nb + 0) * OUT_DIM + c] = acc0;
    h2[(size_t)(n0 + nb + 1) * OUT_DIM + c] = acc1;

    float ws = as2[c], wd = ad2[c];
    float s0 = acc0 * ws, s1 = acc1 * ws;
    float d0 = acc0 * wd, d1 = acc1 * wd;
    #pragma unroll
    for (int o = 32; o > 0; o >>= 1) {
        s0 += __shfl_down(s0, o, 64); s1 += __shfl_down(s1, o, 64);
        d0 += __shfl_down(d0, o, 64); d1 += __shfl_down(d1, o, 64);
    }
    if (c == 0) {
        a_src2[n0 + nb + 0] = s0; a_src2[n0 + nb + 1] = s1;
        a_dst2[n0 + nb + 0] = d0; a_dst2[n0 + nb + 1] = d1;
    }
}

// ---------------- Layer 2: aggregate + log_softmax ----------------

__global__ __launch_bounds__(64) void l2_aggregate(
        const float* __restrict__ h2, const float* __restrict__ a_src2,
        const float* __restrict__ a_dst2, const int* __restrict__ row_start,
        const int* __restrict__ csr_src, const float* __restrict__ b2,
        float* __restrict__ out) {
    int n = blockIdx.x;
    int c = threadIdx.x;
    int beg = row_start[n], end = row_start[n + 1];
    float adst = a_dst2[n];
    float m = -INFINITY, l = 0.f, acc = 0.f;
    for (int j = beg; j < end; ++j) {
        int s = csr_src[j];
        float e = a_src2[s] + adst;
        e = e > 0.f ? e : NEG_SLOPE * e;
        float nm = fmaxf(m, e);
        float sc = __expf(m - nm);
        float p  = __expf(e - nm);
        l = l * sc + p;
        acc = acc * sc + p * h2[(size_t)s * OUT_DIM + c];
        m = nm;
    }
    float o = acc / (l + 1e-16f) + b2[c];
    // log_softmax over 64 channels (one wave)
    float mx = o;
    #pragma unroll
    for (int w = 32; w > 0; w >>= 1) mx = fmaxf(mx, __shfl_xor(mx, w, 64));
    float ex = __expf(o - mx);
    float ssum = ex;
    #pragma unroll
    for (int w = 32; w > 0; w >>= 1) ssum += __shfl_xor(ssum, w, 64);
    out[(size_t)n * OUT_DIM + c] = o - mx - __logf(ssum);
}

// ---------------- launch ----------------

extern "C" void kernel_launch(void* const* d_in, const int* in_sizes, int n_in,
                              void* d_out, int out_size, void* d_ws, size_t ws_size,
                              hipStream_t stream) {
    const float* x   = (const float*)d_in[0];
    const int*   ei  = (const int*)d_in[1];      // [2, E] int32
    const float* W1  = (const float*)d_in[2];
    const float* as1 = (const float*)d_in[3];
    const float* ad1 = (const float*)d_in[4];
    const float* b1  = (const float*)d_in[5];
    const float* W2  = (const float*)d_in[6];
    const float* as2 = (const float*)d_in[7];
    const float* ad2 = (const float*)d_in[8];
    const float* b2  = (const float*)d_in[9];
    float* out = (float*)d_out;

    const int* src = ei;             // row 0
    const int* dst = ei + E_EDGES;   // row 1

    char* ws = (char*)d_ws;
    size_t off = 0;
    auto alloc = [&](size_t bytes) -> void* {
        void* p = ws + off;
        off += (bytes + 255) & ~size_t(255);
        return p;
    };
    float* h1        = (float*)alloc((size_t)N_NODES * HID * 4);
    float* h_act     = (float*)alloc((size_t)N_NODES * HID * 4);
    float* h2        = (float*)alloc((size_t)N_NODES * OUT_DIM * 4);
    float* a_src1    = (float*)alloc((size_t)N_NODES * HEADS * 4);
    float* a_dst1    = (float*)alloc((size_t)N_NODES * HEADS * 4);
    float* a_src2    = (float*)alloc((size_t)N_NODES * 4);
    float* a_dst2    = (float*)alloc((size_t)N_NODES * 4);
    int*   deg       = (int*)alloc((size_t)N_NODES * 4);
    int*   row_start = (int*)alloc((size_t)(N_NODES + 1) * 4);
    int*   cursor    = (int*)alloc((size_t)N_NODES * 4);
    int*   excl      = (int*)alloc((size_t)N_NODES * 4);
    int*   blockSums = (int*)alloc(256 * 4);
    int*   csr_src   = (int*)alloc((size_t)ET * 4);

    hipMemsetAsync(deg, 0, (size_t)N_NODES * 4, stream);

    int etb = (ET + 255) / 256;
    hist_kernel<<<etb, 256, 0, stream>>>(dst, deg);
    scan_block_kernel<<<SCAN_BLOCKS, 256, 0, stream>>>(deg, excl, blockSums);
    scan_sums_kernel<<<1, 256, 0, stream>>>(blockSums);
    scan_add_kernel<<<SCAN_BLOCKS, 256, 0, stream>>>(excl, blockSums, row_start, cursor);
    fill_kernel<<<etb, 256, 0, stream>>>(src, dst, cursor, csr_src);

    l1_transform<<<N_NODES / 8, 256, 0, stream>>>(x, W1, as1, ad1, h1, a_src1, a_dst1);
    l1_aggregate<<<N_NODES, 128, 0, stream>>>(h1, a_src1, a_dst1, row_start, csr_src, b1, h_act);
    l2_transform<<<N_NODES / 8, 256, 0, stream>>>(h_act, W2, as2, ad2, h2, a_src2, a_dst2);
    l2_aggregate<<<N_NODES, 64, 0, stream>>>(h2, a_src2, a_dst2, row_start, csr_src, b2, out);
}

// Round 2
// 375.571 us; speedup vs baseline: 1.1331x; 1.1331x over previous
//
#include <hip/hip_runtime.h>
#include <math.h>

#define N_NODES 50000
#define E_EDGES 800000
#define ET      (E_EDGES + N_NODES)   // edges + self loops
#define IN_DIM  128
#define HID     128
#define HEADS   8
#define C1      16
#define OUT_DIM 64
#define NEG_SLOPE 0.2f

#define SCAN_BLOCKS ((N_NODES + 255) / 256)   // 196

// ---------------- CSR build ----------------

__global__ void hist_kernel(const int* __restrict__ dst, int* __restrict__ deg) {
    int i = blockIdx.x * blockDim.x + threadIdx.x;
    if (i < ET) {
        int d = (i < E_EDGES) ? dst[i] : (i - E_EDGES);
        atomicAdd(&deg[d], 1);
    }
}

__global__ void scan_block_kernel(const int* __restrict__ deg, int* __restrict__ excl,
                                  int* __restrict__ blockSums) {
    __shared__ int s[256];
    int t = threadIdx.x;
    int i = blockIdx.x * 256 + t;
    int v = (i < N_NODES) ? deg[i] : 0;
    s[t] = v;
    __syncthreads();
    #pragma unroll
    for (int off = 1; off < 256; off <<= 1) {
        int add = (t >= off) ? s[t - off] : 0;
        __syncthreads();
        s[t] += add;
        __syncthreads();
    }
    if (i < N_NODES) excl[i] = s[t] - v;
    if (t == 255) blockSums[blockIdx.x] = s[255];
}

__global__ void scan_sums_kernel(int* __restrict__ blockSums) {
    __shared__ int s[256];
    int t = threadIdx.x;
    int v = (t < SCAN_BLOCKS) ? blockSums[t] : 0;
    s[t] = v;
    __syncthreads();
    #pragma unroll
    for (int off = 1; off < 256; off <<= 1) {
        int add = (t >= off) ? s[t - off] : 0;
        __syncthreads();
        s[t] += add;
        __syncthreads();
    }
    if (t < SCAN_BLOCKS) blockSums[t] = s[t] - v;   // exclusive
}

__global__ void scan_add_kernel(const int* __restrict__ excl, const int* __restrict__ blockSums,
                                int* __restrict__ row_start, int* __restrict__ cursor) {
    int i = blockIdx.x * 256 + threadIdx.x;
    if (i < N_NODES) {
        int v = excl[i] + blockSums[blockIdx.x];
        row_start[i] = v;
        cursor[i] = v;
    }
    if (i == 0) row_start[N_NODES] = ET;   // total is static
}

__global__ void fill_kernel(const int* __restrict__ src, const int* __restrict__ dst,
                            int* __restrict__ cursor, int* __restrict__ csr_src) {
    int i = blockIdx.x * blockDim.x + threadIdx.x;
    if (i < ET) {
        int s, d;
        if (i < E_EDGES) { s = src[i]; d = dst[i]; }
        else             { s = d = i - E_EDGES; }
        int pos = atomicAdd(&cursor[d], 1);
        csr_src[pos] = s;
    }
}

// ---------------- Layer 1: transform (x@W1, attention dots) ----------------

__global__ __launch_bounds__(256) void l1_transform(
        const float* __restrict__ x, const float* __restrict__ W1,
        const float* __restrict__ as1, const float* __restrict__ ad1,
        float* __restrict__ h1, float* __restrict__ a_src, float* __restrict__ a_dst) {
    int n0 = blockIdx.x * 8;
    int t = threadIdx.x;
    int c = t & 127;
    int g = t >> 7;          // 0..1 -> nodes g*4 .. g*4+3
    __shared__ float xs[8][IN_DIM];
    for (int i = t; i < 8 * IN_DIM; i += 256) {
        xs[i >> 7][i & 127] = x[(size_t)(n0 + (i >> 7)) * IN_DIM + (i & 127)];
    }
    __syncthreads();
    int nb = g * 4;
    float acc0 = 0.f, acc1 = 0.f, acc2 = 0.f, acc3 = 0.f;
    #pragma unroll 8
    for (int k = 0; k < IN_DIM; ++k) {
        float w = W1[k * HID + c];
        acc0 = fmaf(xs[nb + 0][k], w, acc0);
        acc1 = fmaf(xs[nb + 1][k], w, acc1);
        acc2 = fmaf(xs[nb + 2][k], w, acc2);
        acc3 = fmaf(xs[nb + 3][k], w, acc3);
    }
    h1[(size_t)(n0 + nb + 0) * HID + c] = acc0;
    h1[(size_t)(n0 + nb + 1) * HID + c] = acc1;
    h1[(size_t)(n0 + nb + 2) * HID + c] = acc2;
    h1[(size_t)(n0 + nb + 3) * HID + c] = acc3;

    int h = c >> 4;
    float ws = as1[c], wd = ad1[c];
    float s0 = acc0 * ws, s1 = acc1 * ws, s2 = acc2 * ws, s3 = acc3 * ws;
    float d0 = acc0 * wd, d1 = acc1 * wd, d2 = acc2 * wd, d3 = acc3 * wd;
    #pragma unroll
    for (int o = 8; o > 0; o >>= 1) {
        s0 += __shfl_down(s0, o, 16); s1 += __shfl_down(s1, o, 16);
        s2 += __shfl_down(s2, o, 16); s3 += __shfl_down(s3, o, 16);
        d0 += __shfl_down(d0, o, 16); d1 += __shfl_down(d1, o, 16);
        d2 += __shfl_down(d2, o, 16); d3 += __shfl_down(d3, o, 16);
    }
    if ((c & 15) == 0) {
        a_src[(n0 + nb + 0) * HEADS + h] = s0;
        a_src[(n0 + nb + 1) * HEADS + h] = s1;
        a_src[(n0 + nb + 2) * HEADS + h] = s2;
        a_src[(n0 + nb + 3) * HEADS + h] = s3;
        a_dst[(n0 + nb + 0) * HEADS + h] = d0;
        a_dst[(n0 + nb + 1) * HEADS + h] = d1;
        a_dst[(n0 + nb + 2) * HEADS + h] = d2;
        a_dst[(n0 + nb + 3) * HEADS + h] = d3;
    }
}

// ---------------- Layer 1: aggregate ----------------
// 1 wave per node (2 nodes / 128-block). Lane owns 2 channels (float2).
// Single-exp online softmax; edge loop unrolled x4 for MLP.

__global__ __launch_bounds__(128) void l1_aggregate(
        const float* __restrict__ h1, const float* __restrict__ a_src,
        const float* __restrict__ a_dst, const int* __restrict__ row_start,
        const int* __restrict__ csr_src, const float* __restrict__ b1,
        float* __restrict__ h_act) {
    int w = threadIdx.x >> 6;
    int lane = threadIdx.x & 63;
    int n = blockIdx.x * 2 + w;
    int c0 = lane * 2;
    int h = lane >> 3;          // (2*lane)>>4
    int beg = row_start[n], end = row_start[n + 1];
    float adst = a_dst[n * HEADS + h];
    float m = -INFINITY, l = 0.f, accx = 0.f, accy = 0.f;

    auto update = [&](float e, float2 v) {
        e += adst;
        e = fmaxf(e, NEG_SLOPE * e);          // leaky relu
        float nm = fmaxf(m, e);
        float d = e - m;                      // +inf on first iter
        float t = __expf(-fabsf(d));
        float sc = (d >= 0.f) ? t : 1.f;
        float p  = (d >= 0.f) ? 1.f : t;
        l = fmaf(l, sc, p);
        accx = fmaf(accx, sc, p * v.x);
        accy = fmaf(accy, sc, p * v.y);
        m = nm;
    };

    int j = beg;
    for (; j + 4 <= end; j += 4) {
        int s0 = csr_src[j + 0], s1 = csr_src[j + 1];
        int s2 = csr_src[j + 2], s3 = csr_src[j + 3];
        float e0 = a_src[s0 * HEADS + h];
        float e1 = a_src[s1 * HEADS + h];
        float e2 = a_src[s2 * HEADS + h];
        float e3 = a_src[s3 * HEADS + h];
        float2 v0 = *(const float2*)&h1[(size_t)s0 * HID + c0];
        float2 v1 = *(const float2*)&h1[(size_t)s1 * HID + c0];
        float2 v2 = *(const float2*)&h1[(size_t)s2 * HID + c0];
        float2 v3 = *(const float2*)&h1[(size_t)s3 * HID + c0];
        update(e0, v0); update(e1, v1); update(e2, v2); update(e3, v3);
    }
    for (; j < end; ++j) {
        int s = csr_src[j];
        float e = a_src[s * HEADS + h];
        float2 v = *(const float2*)&h1[(size_t)s * HID + c0];
        update(e, v);
    }

    float inv = 1.f / (l + 1e-16f);
    float vx = accx * inv + b1[c0];
    float vy = accy * inv + b1[c0 + 1];
    vx = vx > 0.f ? vx : (__expf(vx) - 1.f);   // ELU
    vy = vy > 0.f ? vy : (__expf(vy) - 1.f);
    float2 o = make_float2(vx, vy);
    *(float2*)&h_act[(size_t)n * HID + c0] = o;
}

// ---------------- Layer 2: transform ----------------

__global__ __launch_bounds__(256) void l2_transform(
        const float* __restrict__ h_act, const float* __restrict__ W2,
        const float* __restrict__ as2, const float* __restrict__ ad2,
        float* __restrict__ h2, float* __restrict__ a_src2, float* __restrict__ a_dst2) {
    int n0 = blockIdx.x * 8;
    int t = threadIdx.x;
    int c = t & 63;
    int g = t >> 6;          // 0..3 -> nodes g*2, g*2+1
    __shared__ float hs[8][HID];
    for (int i = t; i < 8 * HID; i += 256) {
        hs[i >> 7][i & 127] = h_act[(size_t)(n0 + (i >> 7)) * HID + (i & 127)];
    }
    __syncthreads();
    int nb = g * 2;
    float acc0 = 0.f, acc1 = 0.f;
    #pragma unroll 8
    for (int k = 0; k < HID; ++k) {
        float w = W2[k * OUT_DIM + c];
        acc0 = fmaf(hs[nb + 0][k], w, acc0);
        acc1 = fmaf(hs[nb + 1][k], w, acc1);
    }
    h2[(size_t)(n0 + nb + 0) * OUT_DIM + c] = acc0;
    h2[(size_t)(n0 + nb + 1) * OUT_DIM + c] = acc1;

    float ws = as2[c], wd = ad2[c];
    float s0 = acc0 * ws, s1 = acc1 * ws;
    float d0 = acc0 * wd, d1 = acc1 * wd;
    #pragma unroll
    for (int o = 32; o > 0; o >>= 1) {
        s0 += __shfl_down(s0, o, 64); s1 += __shfl_down(s1, o, 64);
        d0 += __shfl_down(d0, o, 64); d1 += __shfl_down(d1, o, 64);
    }
    if (c == 0) {
        a_src2[n0 + nb + 0] = s0; a_src2[n0 + nb + 1] = s1;
        a_dst2[n0 + nb + 0] = d0; a_dst2[n0 + nb + 1] = d1;
    }
}

// ---------------- Layer 2: aggregate + log_softmax ----------------
// 1 wave per node (2 nodes / 128-block). Lane owns 1 channel.

__global__ __launch_bounds__(128) void l2_aggregate(
        const float* __restrict__ h2, const float* __restrict__ a_src2,
        const float* __restrict__ a_dst2, const int* __restrict__ row_start,
        const int* __restrict__ csr_src, const float* __restrict__ b2,
        float* __restrict__ out) {
    int w = threadIdx.x >> 6;
    int lane = threadIdx.x & 63;
    int n = blockIdx.x * 2 + w;
    int beg = row_start[n], end = row_start[n + 1];
    float adst = a_dst2[n];
    float m = -INFINITY, l = 0.f, acc = 0.f;

    auto update = [&](float e, float v) {
        e += adst;
        e = fmaxf(e, NEG_SLOPE * e);
        float nm = fmaxf(m, e);
        float d = e - m;
        float t = __expf(-fabsf(d));
        float sc = (d >= 0.f) ? t : 1.f;
        float p  = (d >= 0.f) ? 1.f : t;
        l = fmaf(l, sc, p);
        acc = fmaf(acc, sc, p * v);
        m = nm;
    };

    int j = beg;
    for (; j + 4 <= end; j += 4) {
        int s0 = csr_src[j + 0], s1 = csr_src[j + 1];
        int s2 = csr_src[j + 2], s3 = csr_src[j + 3];
        float e0 = a_src2[s0], e1 = a_src2[s1];
        float e2 = a_src2[s2], e3 = a_src2[s3];
        float v0 = h2[(size_t)s0 * OUT_DIM + lane];
        float v1 = h2[(size_t)s1 * OUT_DIM + lane];
        float v2 = h2[(size_t)s2 * OUT_DIM + lane];
        float v3 = h2[(size_t)s3 * OUT_DIM + lane];
        update(e0, v0); update(e1, v1); update(e2, v2); update(e3, v3);
    }
    for (; j < end; ++j) {
        int s = csr_src[j];
        update(a_src2[s], h2[(size_t)s * OUT_DIM + lane]);
    }

    float o = acc / (l + 1e-16f) + b2[lane];
    // log_softmax over 64 channels (one wave)
    float mx = o;
    #pragma unroll
    for (int ww = 32; ww > 0; ww >>= 1) mx = fmaxf(mx, __shfl_xor(mx, ww, 64));
    float ex = __expf(o - mx);
    float ssum = ex;
    #pragma unroll
    for (int ww = 32; ww > 0; ww >>= 1) ssum += __shfl_xor(ssum, ww, 64);
    out[(size_t)n * OUT_DIM + lane] = o - mx - __logf(ssum);
}

// ---------------- launch ----------------

extern "C" void kernel_launch(void* const* d_in, const int* in_sizes, int n_in,
                              void* d_out, int out_size, void* d_ws, size_t ws_size,
                              hipStream_t stream) {
    const float* x   = (const float*)d_in[0];
    const int*   ei  = (const int*)d_in[1];
    const float* W1  = (const float*)d_in[2];
    const float* as1 = (const float*)d_in[3];
    const float* ad1 = (const float*)d_in[4];
    const float* b1  = (const float*)d_in[5];
    const float* W2  = (const float*)d_in[6];
    const float* as2 = (const float*)d_in[7];
    const float* ad2 = (const float*)d_in[8];
    const float* b2  = (const float*)d_in[9];
    float* out = (float*)d_out;

    const int* src = ei;             // row 0
    const int* dst = ei + E_EDGES;   // row 1

    char* ws = (char*)d_ws;
    size_t off = 0;
    auto alloc = [&](size_t bytes) -> void* {
        void* p = ws + off;
        off += (bytes + 255) & ~size_t(255);
        return p;
    };
    float* h1        = (float*)alloc((size_t)N_NODES * HID * 4);
    float* h_act     = (float*)alloc((size_t)N_NODES * HID * 4);
    float* h2        = (float*)alloc((size_t)N_NODES * OUT_DIM * 4);
    float* a_src1    = (float*)alloc((size_t)N_NODES * HEADS * 4);
    float* a_dst1    = (float*)alloc((size_t)N_NODES * HEADS * 4);
    float* a_src2    = (float*)alloc((size_t)N_NODES * 4);
    float* a_dst2    = (float*)alloc((size_t)N_NODES * 4);
    int*   deg       = (int*)alloc((size_t)N_NODES * 4);
    int*   row_start = (int*)alloc((size_t)(N_NODES + 1) * 4);
    int*   cursor    = (int*)alloc((size_t)N_NODES * 4);
    int*   excl      = (int*)alloc((size_t)N_NODES * 4);
    int*   blockSums = (int*)alloc(256 * 4);
    int*   csr_src   = (int*)alloc((size_t)ET * 4);

    hipMemsetAsync(deg, 0, (size_t)N_NODES * 4, stream);

    int etb = (ET + 255) / 256;
    hist_kernel<<<etb, 256, 0, stream>>>(dst, deg);
    scan_block_kernel<<<SCAN_BLOCKS, 256, 0, stream>>>(deg, excl, blockSums);
    scan_sums_kernel<<<1, 256, 0, stream>>>(blockSums);
    scan_add_kernel<<<SCAN_BLOCKS, 256, 0, stream>>>(excl, blockSums, row_start, cursor);
    fill_kernel<<<etb, 256, 0, stream>>>(src, dst, cursor, csr_src);

    l1_transform<<<N_NODES / 8, 256, 0, stream>>>(x, W1, as1, ad1, h1, a_src1, a_dst1);
    l1_aggregate<<<N_NODES / 2, 128, 0, stream>>>(h1, a_src1, a_dst1, row_start, csr_src, b1, h_act);
    l2_transform<<<N_NODES / 8, 256, 0, stream>>>(h_act, W2, as2, ad2, h2, a_src2, a_dst2);
    l2_aggregate<<<N_NODES / 2, 128, 0, stream>>>(h2, a_src2, a_dst2, row_start, csr_src, b2, out);
}

// Round 3
// 349.486 us; speedup vs baseline: 1.2176x; 1.0746x over previous
//
#include <hip/hip_runtime.h>
#include <math.h>

#define N_NODES 50000
#define E_EDGES 800000
#define ET      (E_EDGES + N_NODES)   // edges + self loops
#define IN_DIM  128
#define HID     128
#define HEADS   8
#define C1      16
#define OUT_DIM 64
#define NEG_SLOPE 0.2f

#define SCAN_BLOCKS ((N_NODES + 255) / 256)   // 196

typedef unsigned int uint32;
typedef unsigned short ushort16;

static __device__ __forceinline__ unsigned short f2bf(float f) {
    uint32 u = __float_as_uint(f);
    u += 0x7FFFu + ((u >> 16) & 1u);   // round to nearest even
    return (unsigned short)(u >> 16);
}

// ---------------- CSR build ----------------

__global__ void hist_kernel(const int* __restrict__ dst, int* __restrict__ deg) {
    int i = blockIdx.x * blockDim.x + threadIdx.x;
    if (i < ET) {
        int d = (i < E_EDGES) ? dst[i] : (i - E_EDGES);
        atomicAdd(&deg[d], 1);
    }
}

__global__ void scan_block_kernel(const int* __restrict__ deg, int* __restrict__ excl,
                                  int* __restrict__ blockSums) {
    __shared__ int s[256];
    int t = threadIdx.x;
    int i = blockIdx.x * 256 + t;
    int v = (i < N_NODES) ? deg[i] : 0;
    s[t] = v;
    __syncthreads();
    #pragma unroll
    for (int off = 1; off < 256; off <<= 1) {
        int add = (t >= off) ? s[t - off] : 0;
        __syncthreads();
        s[t] += add;
        __syncthreads();
    }
    if (i < N_NODES) excl[i] = s[t] - v;
    if (t == 255) blockSums[blockIdx.x] = s[255];
}

__global__ void scan_sums_kernel(int* __restrict__ blockSums) {
    __shared__ int s[256];
    int t = threadIdx.x;
    int v = (t < SCAN_BLOCKS) ? blockSums[t] : 0;
    s[t] = v;
    __syncthreads();
    #pragma unroll
    for (int off = 1; off < 256; off <<= 1) {
        int add = (t >= off) ? s[t - off] : 0;
        __syncthreads();
        s[t] += add;
        __syncthreads();
    }
    if (t < SCAN_BLOCKS) blockSums[t] = s[t] - v;   // exclusive
}

__global__ void scan_add_kernel(const int* __restrict__ excl, const int* __restrict__ blockSums,
                                int* __restrict__ row_start, int* __restrict__ cursor) {
    int i = blockIdx.x * 256 + threadIdx.x;
    if (i < N_NODES) {
        int v = excl[i] + blockSums[blockIdx.x];
        row_start[i] = v;
        cursor[i] = v;
    }
    if (i == 0) row_start[N_NODES] = ET;   // total is static
}

__global__ void fill_kernel(const int* __restrict__ src, const int* __restrict__ dst,
                            int* __restrict__ cursor, int* __restrict__ csr_src) {
    int i = blockIdx.x * blockDim.x + threadIdx.x;
    if (i < ET) {
        int s, d;
        if (i < E_EDGES) { s = src[i]; d = dst[i]; }
        else             { s = d = i - E_EDGES; }
        int pos = atomicAdd(&cursor[d], 1);
        csr_src[pos] = s;
    }
}

// ---------------- Layer 1: transform (x@W1, attention dots) ----------------
// h1 is written as bf16 (ushort[N][128]) for the gather-heavy aggregation.

__global__ __launch_bounds__(256) void l1_transform(
        const float* __restrict__ x, const float* __restrict__ W1,
        const float* __restrict__ as1, const float* __restrict__ ad1,
        unsigned short* __restrict__ h1b, float* __restrict__ a_src, float* __restrict__ a_dst) {
    int n0 = blockIdx.x * 8;
    int t = threadIdx.x;
    int c = t & 127;
    int g = t >> 7;          // 0..1 -> nodes g*4 .. g*4+3
    __shared__ float xs[8][IN_DIM];
    for (int i = t; i < 8 * IN_DIM; i += 256) {
        xs[i >> 7][i & 127] = x[(size_t)(n0 + (i >> 7)) * IN_DIM + (i & 127)];
    }
    __syncthreads();
    int nb = g * 4;
    float acc0 = 0.f, acc1 = 0.f, acc2 = 0.f, acc3 = 0.f;
    #pragma unroll 8
    for (int k = 0; k < IN_DIM; ++k) {
        float w = W1[k * HID + c];
        acc0 = fmaf(xs[nb + 0][k], w, acc0);
        acc1 = fmaf(xs[nb + 1][k], w, acc1);
        acc2 = fmaf(xs[nb + 2][k], w, acc2);
        acc3 = fmaf(xs[nb + 3][k], w, acc3);
    }
    h1b[(size_t)(n0 + nb + 0) * HID + c] = f2bf(acc0);
    h1b[(size_t)(n0 + nb + 1) * HID + c] = f2bf(acc1);
    h1b[(size_t)(n0 + nb + 2) * HID + c] = f2bf(acc2);
    h1b[(size_t)(n0 + nb + 3) * HID + c] = f2bf(acc3);

    int h = c >> 4;
    float ws = as1[c], wd = ad1[c];
    float s0 = acc0 * ws, s1 = acc1 * ws, s2 = acc2 * ws, s3 = acc3 * ws;
    float d0 = acc0 * wd, d1 = acc1 * wd, d2 = acc2 * wd, d3 = acc3 * wd;
    #pragma unroll
    for (int o = 8; o > 0; o >>= 1) {
        s0 += __shfl_down(s0, o, 16); s1 += __shfl_down(s1, o, 16);
        s2 += __shfl_down(s2, o, 16); s3 += __shfl_down(s3, o, 16);
        d0 += __shfl_down(d0, o, 16); d1 += __shfl_down(d1, o, 16);
        d2 += __shfl_down(d2, o, 16); d3 += __shfl_down(d3, o, 16);
    }
    if ((c & 15) == 0) {
        a_src[(n0 + nb + 0) * HEADS + h] = s0;
        a_src[(n0 + nb + 1) * HEADS + h] = s1;
        a_src[(n0 + nb + 2) * HEADS + h] = s2;
        a_src[(n0 + nb + 3) * HEADS + h] = s3;
        a_dst[(n0 + nb + 0) * HEADS + h] = d0;
        a_dst[(n0 + nb + 1) * HEADS + h] = d1;
        a_dst[(n0 + nb + 2) * HEADS + h] = d2;
        a_dst[(n0 + nb + 3) * HEADS + h] = d3;
    }
}

// ---------------- Layer 1: aggregate ----------------
// 1 wave per node (2 nodes / 128-block). Lane owns 2 bf16 channels (one dword gather).
// Single-exp online softmax; edge loop unrolled x4 for MLP.

__global__ __launch_bounds__(128) void l1_aggregate(
        const unsigned short* __restrict__ h1b, const float* __restrict__ a_src,
        const float* __restrict__ a_dst, const int* __restrict__ row_start,
        const int* __restrict__ csr_src, const float* __restrict__ b1,
        float* __restrict__ h_act) {
    int w = threadIdx.x >> 6;
    int lane = threadIdx.x & 63;
    int n = blockIdx.x * 2 + w;
    int c0 = lane * 2;
    int h = lane >> 3;          // (2*lane)>>4
    int beg = row_start[n], end = row_start[n + 1];
    float adst = a_dst[n * HEADS + h];
    float m = -INFINITY, l = 0.f, accx = 0.f, accy = 0.f;

    auto update = [&](float e, uint32 u) {
        float vx = __uint_as_float(u << 16);
        float vy = __uint_as_float(u & 0xFFFF0000u);
        e += adst;
        e = fmaxf(e, NEG_SLOPE * e);          // leaky relu
        float nm = fmaxf(m, e);
        float d = e - m;                      // +inf on first iter
        float t = __expf(-fabsf(d));
        float sc = (d >= 0.f) ? t : 1.f;
        float p  = (d >= 0.f) ? 1.f : t;
        l = fmaf(l, sc, p);
        accx = fmaf(accx, sc, p * vx);
        accy = fmaf(accy, sc, p * vy);
        m = nm;
    };

    int j = beg;
    for (; j + 4 <= end; j += 4) {
        int s0 = csr_src[j + 0], s1 = csr_src[j + 1];
        int s2 = csr_src[j + 2], s3 = csr_src[j + 3];
        float e0 = a_src[s0 * HEADS + h];
        float e1 = a_src[s1 * HEADS + h];
        float e2 = a_src[s2 * HEADS + h];
        float e3 = a_src[s3 * HEADS + h];
        uint32 u0 = *(const uint32*)&h1b[(size_t)s0 * HID + c0];
        uint32 u1 = *(const uint32*)&h1b[(size_t)s1 * HID + c0];
        uint32 u2 = *(const uint32*)&h1b[(size_t)s2 * HID + c0];
        uint32 u3 = *(const uint32*)&h1b[(size_t)s3 * HID + c0];
        update(e0, u0); update(e1, u1); update(e2, u2); update(e3, u3);
    }
    for (; j < end; ++j) {
        int s = csr_src[j];
        float e = a_src[s * HEADS + h];
        uint32 u = *(const uint32*)&h1b[(size_t)s * HID + c0];
        update(e, u);
    }

    float inv = 1.f / (l + 1e-16f);
    float vx = accx * inv + b1[c0];
    float vy = accy * inv + b1[c0 + 1];
    vx = vx > 0.f ? vx : (__expf(vx) - 1.f);   // ELU
    vy = vy > 0.f ? vy : (__expf(vy) - 1.f);
    float2 o = make_float2(vx, vy);
    *(float2*)&h_act[(size_t)n * HID + c0] = o;
}

// ---------------- Layer 2: transform ----------------
// h2 written as bf16 (ushort[N][64]) for the gather in l2_aggregate.

__global__ __launch_bounds__(256) void l2_transform(
        const float* __restrict__ h_act, const float* __restrict__ W2,
        const float* __restrict__ as2, const float* __restrict__ ad2,
        unsigned short* __restrict__ h2b, float* __restrict__ a_src2, float* __restrict__ a_dst2) {
    int n0 = blockIdx.x * 8;
    int t = threadIdx.x;
    int c = t & 63;
    int g = t >> 6;          // 0..3 -> nodes g*2, g*2+1
    __shared__ float hs[8][HID];
    for (int i = t; i < 8 * HID; i += 256) {
        hs[i >> 7][i & 127] = h_act[(size_t)(n0 + (i >> 7)) * HID + (i & 127)];
    }
    __syncthreads();
    int nb = g * 2;
    float acc0 = 0.f, acc1 = 0.f;
    #pragma unroll 8
    for (int k = 0; k < HID; ++k) {
        float w = W2[k * OUT_DIM + c];
        acc0 = fmaf(hs[nb + 0][k], w, acc0);
        acc1 = fmaf(hs[nb + 1][k], w, acc1);
    }
    h2b[(size_t)(n0 + nb + 0) * OUT_DIM + c] = f2bf(acc0);
    h2b[(size_t)(n0 + nb + 1) * OUT_DIM + c] = f2bf(acc1);

    float ws = as2[c], wd = ad2[c];
    float s0 = acc0 * ws, s1 = acc1 * ws;
    float d0 = acc0 * wd, d1 = acc1 * wd;
    #pragma unroll
    for (int o = 32; o > 0; o >>= 1) {
        s0 += __shfl_down(s0, o, 64); s1 += __shfl_down(s1, o, 64);
        d0 += __shfl_down(d0, o, 64); d1 += __shfl_down(d1, o, 64);
    }
    if (c == 0) {
        a_src2[n0 + nb + 0] = s0; a_src2[n0 + nb + 1] = s1;
        a_dst2[n0 + nb + 0] = d0; a_dst2[n0 + nb + 1] = d1;
    }
}

// ---------------- Layer 2: aggregate + log_softmax ----------------
// 1 wave per node (2 nodes / 128-block). Lane owns 1 channel (bf16 gather).

__global__ __launch_bounds__(128) void l2_aggregate(
        const unsigned short* __restrict__ h2b, const float* __restrict__ a_src2,
        const float* __restrict__ a_dst2, const int* __restrict__ row_start,
        const int* __restrict__ csr_src, const float* __restrict__ b2,
        float* __restrict__ out) {
    int w = threadIdx.x >> 6;
    int lane = threadIdx.x & 63;
    int n = blockIdx.x * 2 + w;
    int beg = row_start[n], end = row_start[n + 1];
    float adst = a_dst2[n];
    float m = -INFINITY, l = 0.f, acc = 0.f;

    auto update = [&](float e, unsigned short us) {
        float v = __uint_as_float(((uint32)us) << 16);
        e += adst;
        e = fmaxf(e, NEG_SLOPE * e);
        float nm = fmaxf(m, e);
        float d = e - m;
        float t = __expf(-fabsf(d));
        float sc = (d >= 0.f) ? t : 1.f;
        float p  = (d >= 0.f) ? 1.f : t;
        l = fmaf(l, sc, p);
        acc = fmaf(acc, sc, p * v);
        m = nm;
    };

    int j = beg;
    for (; j + 4 <= end; j += 4) {
        int s0 = csr_src[j + 0], s1 = csr_src[j + 1];
        int s2 = csr_src[j + 2], s3 = csr_src[j + 3];
        float e0 = a_src2[s0], e1 = a_src2[s1];
        float e2 = a_src2[s2], e3 = a_src2[s3];
        unsigned short v0 = h2b[(size_t)s0 * OUT_DIM + lane];
        unsigned short v1 = h2b[(size_t)s1 * OUT_DIM + lane];
        unsigned short v2 = h2b[(size_t)s2 * OUT_DIM + lane];
        unsigned short v3 = h2b[(size_t)s3 * OUT_DIM + lane];
        update(e0, v0); update(e1, v1); update(e2, v2); update(e3, v3);
    }
    for (; j < end; ++j) {
        int s = csr_src[j];
        update(a_src2[s], h2b[(size_t)s * OUT_DIM + lane]);
    }

    float o = acc / (l + 1e-16f) + b2[lane];
    // log_softmax over 64 channels (one wave)
    float mx = o;
    #pragma unroll
    for (int ww = 32; ww > 0; ww >>= 1) mx = fmaxf(mx, __shfl_xor(mx, ww, 64));
    float ex = __expf(o - mx);
    float ssum = ex;
    #pragma unroll
    for (int ww = 32; ww > 0; ww >>= 1) ssum += __shfl_xor(ssum, ww, 64);
    out[(size_t)n * OUT_DIM + lane] = o - mx - __logf(ssum);
}

// ---------------- launch ----------------

extern "C" void kernel_launch(void* const* d_in, const int* in_sizes, int n_in,
                              void* d_out, int out_size, void* d_ws, size_t ws_size,
                              hipStream_t stream) {
    const float* x   = (const float*)d_in[0];
    const int*   ei  = (const int*)d_in[1];
    const float* W1  = (const float*)d_in[2];
    const float* as1 = (const float*)d_in[3];
    const float* ad1 = (const float*)d_in[4];
    const float* b1  = (const float*)d_in[5];
    const float* W2  = (const float*)d_in[6];
    const float* as2 = (const float*)d_in[7];
    const float* ad2 = (const float*)d_in[8];
    const float* b2  = (const float*)d_in[9];
    float* out = (float*)d_out;

    const int* src = ei;             // row 0
    const int* dst = ei + E_EDGES;   // row 1

    char* ws = (char*)d_ws;
    size_t off = 0;
    auto alloc = [&](size_t bytes) -> void* {
        void* p = ws + off;
        off += (bytes + 255) & ~size_t(255);
        return p;
    };
    unsigned short* h1b = (unsigned short*)alloc((size_t)N_NODES * HID * 2);
    float* h_act        = (float*)alloc((size_t)N_NODES * HID * 4);
    unsigned short* h2b = (unsigned short*)alloc((size_t)N_NODES * OUT_DIM * 2);
    float* a_src1    = (float*)alloc((size_t)N_NODES * HEADS * 4);
    float* a_dst1    = (float*)alloc((size_t)N_NODES * HEADS * 4);
    float* a_src2    = (float*)alloc((size_t)N_NODES * 4);
    float* a_dst2    = (float*)alloc((size_t)N_NODES * 4);
    int*   deg       = (int*)alloc((size_t)N_NODES * 4);
    int*   row_start = (int*)alloc((size_t)(N_NODES + 1) * 4);
    int*   cursor    = (int*)alloc((size_t)N_NODES * 4);
    int*   excl      = (int*)alloc((size_t)N_NODES * 4);
    int*   blockSums = (int*)alloc(256 * 4);
    int*   csr_src   = (int*)alloc((size_t)ET * 4);

    hipMemsetAsync(deg, 0, (size_t)N_NODES * 4, stream);

    int etb = (ET + 255) / 256;
    hist_kernel<<<etb, 256, 0, stream>>>(dst, deg);
    scan_block_kernel<<<SCAN_BLOCKS, 256, 0, stream>>>(deg, excl, blockSums);
    scan_sums_kernel<<<1, 256, 0, stream>>>(blockSums);
    scan_add_kernel<<<SCAN_BLOCKS, 256, 0, stream>>>(excl, blockSums, row_start, cursor);
    fill_kernel<<<etb, 256, 0, stream>>>(src, dst, cursor, csr_src);

    l1_transform<<<N_NODES / 8, 256, 0, stream>>>(x, W1, as1, ad1, h1b, a_src1, a_dst1);
    l1_aggregate<<<N_NODES / 2, 128, 0, stream>>>(h1b, a_src1, a_dst1, row_start, csr_src, b1, h_act);
    l2_transform<<<N_NODES / 8, 256, 0, stream>>>(h_act, W2, as2, ad2, h2b, a_src2, a_dst2);
    l2_aggregate<<<N_NODES / 2, 128, 0, stream>>>(h2b, a_src2, a_dst2, row_start, csr_src, b2, out);
}

// Round 4
// 303.656 us; speedup vs baseline: 1.4014x; 1.1509x over previous
//
#include <hip/hip_runtime.h>
#include <math.h>

#define N_NODES 50000
#define E_EDGES 800000
#define ET      (E_EDGES + N_NODES)   // edges + self loops
#define IN_DIM  128
#define HID     128
#define HEADS   8
#define C1      16
#define OUT_DIM 64
#define NEG_SLOPE 0.2f

#define TILE    8192
#define NT      ((ET + TILE - 1) / TILE)      // 104 tiles
#define NB      ((N_NODES + 255) / 256)       // 196 buckets of 256 nodes

typedef unsigned int uint32;

static __device__ __forceinline__ unsigned short f2bf(float f) {
    uint32 u = __float_as_uint(f);
    u += 0x7FFFu + ((u >> 16) & 1u);   // round to nearest even
    return (unsigned short)(u >> 16);
}

// ---------------- CSR build: two-level bucket sort, no global atomics ----------------
// Bucket = dst >> 8 (256 nodes per bucket). Phase 1 groups edges by bucket with
// per-tile contiguous output runs; phase 2 builds per-node rows inside each
// bucket's private ~18KB region (stays in one XCD's L2).

__global__ __launch_bounds__(256) void bucket_hist(
        const int* __restrict__ dst, int* __restrict__ cnt /* [NB][NT] */) {
    __shared__ int hist[NB];
    int t = threadIdx.x;
    for (int b = t; b < NB; b += 256) hist[b] = 0;
    __syncthreads();
    int base = blockIdx.x * TILE;
    #pragma unroll
    for (int it = 0; it < TILE / 256; ++it) {
        int i = base + it * 256 + t;
        if (i < ET) {
            int d = (i < E_EDGES) ? dst[i] : (i - E_EDGES);
            atomicAdd(&hist[d >> 8], 1);
        }
    }
    __syncthreads();
    for (int b = t; b < NB; b += 256) cnt[b * NT + blockIdx.x] = hist[b];
}

__global__ __launch_bounds__(256) void bucket_scan(
        const int* __restrict__ cnt, int* __restrict__ tileOff /* [NB][NT] */,
        int* __restrict__ bucketStart /* [NB+1] */) {
    __shared__ int s[256];
    int t = threadIdx.x;
    int total = 0;
    if (t < NB) {
        int run = 0;
        for (int k = 0; k < NT; ++k) {
            int c = cnt[t * NT + k];
            tileOff[t * NT + k] = run;
            run += c;
        }
        total = run;
    }
    s[t] = total;
    __syncthreads();
    #pragma unroll
    for (int off = 1; off < 256; off <<= 1) {
        int add = (t >= off) ? s[t - off] : 0;
        __syncthreads();
        s[t] += add;
        __syncthreads();
    }
    if (t < NB) bucketStart[t] = s[t] - total;   // exclusive
    if (t == 0) bucketStart[NB] = ET;
}

__global__ __launch_bounds__(256) void bucket_scatter(
        const int* __restrict__ src, const int* __restrict__ dst,
        const int* __restrict__ tileOff, const int* __restrict__ bucketStart,
        int2* __restrict__ pairs) {
    __shared__ int cur[NB];
    int t = threadIdx.x;
    for (int b = t; b < NB; b += 256)
        cur[b] = bucketStart[b] + tileOff[b * NT + blockIdx.x];
    __syncthreads();
    int base = blockIdx.x * TILE;
    #pragma unroll
    for (int it = 0; it < TILE / 256; ++it) {
        int i = base + it * 256 + t;
        if (i < ET) {
            int s, d;
            if (i < E_EDGES) { s = src[i]; d = dst[i]; }
            else             { s = d = i - E_EDGES; }
            int pos = atomicAdd(&cur[d >> 8], 1);
            pairs[pos] = make_int2(s, d);
        }
    }
}

__global__ __launch_bounds__(256) void bucket_build(
        const int2* __restrict__ pairs, const int* __restrict__ bucketStart,
        int* __restrict__ row_start, int* __restrict__ csr_src) {
    __shared__ int sdeg[256];
    __shared__ int sscan[256];
    int t = threadIdx.x;
    int b = blockIdx.x;
    int beg = bucketStart[b], end = bucketStart[b + 1];
    sdeg[t] = 0;
    __syncthreads();
    for (int j = beg + t; j < end; j += 256)
        atomicAdd(&sdeg[pairs[j].y & 255], 1);
    __syncthreads();
    int v = sdeg[t];
    sscan[t] = v;
    __syncthreads();
    #pragma unroll
    for (int off = 1; off < 256; off <<= 1) {
        int add = (t >= off) ? sscan[t - off] : 0;
        __syncthreads();
        sscan[t] += add;
        __syncthreads();
    }
    int pos0 = beg + sscan[t] - v;   // exclusive prefix within bucket
    int n = b * 256 + t;
    if (n < N_NODES) row_start[n] = pos0;
    if (b == 0 && t == 0) row_start[N_NODES] = ET;
    __syncthreads();
    sscan[t] = pos0;                 // reuse as cursor
    __syncthreads();
    for (int j = beg + t; j < end; j += 256) {
        int2 p = pairs[j];
        int pos = atomicAdd(&sscan[p.y & 255], 1);
        csr_src[pos] = p.x;
    }
}

// ---------------- Layer 1: transform (x@W1, attention dots) ----------------
// h1 is written as bf16 (ushort[N][128]) for the gather-heavy aggregation.

__global__ __launch_bounds__(256) void l1_transform(
        const float* __restrict__ x, const float* __restrict__ W1,
        const float* __restrict__ as1, const float* __restrict__ ad1,
        unsigned short* __restrict__ h1b, float* __restrict__ a_src, float* __restrict__ a_dst) {
    int n0 = blockIdx.x * 8;
    int t = threadIdx.x;
    int c = t & 127;
    int g = t >> 7;          // 0..1 -> nodes g*4 .. g*4+3
    __shared__ float xs[8][IN_DIM];
    for (int i = t; i < 8 * IN_DIM; i += 256) {
        xs[i >> 7][i & 127] = x[(size_t)(n0 + (i >> 7)) * IN_DIM + (i & 127)];
    }
    __syncthreads();
    int nb = g * 4;
    float acc0 = 0.f, acc1 = 0.f, acc2 = 0.f, acc3 = 0.f;
    #pragma unroll 8
    for (int k = 0; k < IN_DIM; ++k) {
        float w = W1[k * HID + c];
        acc0 = fmaf(xs[nb + 0][k], w, acc0);
        acc1 = fmaf(xs[nb + 1][k], w, acc1);
        acc2 = fmaf(xs[nb + 2][k], w, acc2);
        acc3 = fmaf(xs[nb + 3][k], w, acc3);
    }
    h1b[(size_t)(n0 + nb + 0) * HID + c] = f2bf(acc0);
    h1b[(size_t)(n0 + nb + 1) * HID + c] = f2bf(acc1);
    h1b[(size_t)(n0 + nb + 2) * HID + c] = f2bf(acc2);
    h1b[(size_t)(n0 + nb + 3) * HID + c] = f2bf(acc3);

    int h = c >> 4;
    float ws = as1[c], wd = ad1[c];
    float s0 = acc0 * ws, s1 = acc1 * ws, s2 = acc2 * ws, s3 = acc3 * ws;
    float d0 = acc0 * wd, d1 = acc1 * wd, d2 = acc2 * wd, d3 = acc3 * wd;
    #pragma unroll
    for (int o = 8; o > 0; o >>= 1) {
        s0 += __shfl_down(s0, o, 16); s1 += __shfl_down(s1, o, 16);
        s2 += __shfl_down(s2, o, 16); s3 += __shfl_down(s3, o, 16);
        d0 += __shfl_down(d0, o, 16); d1 += __shfl_down(d1, o, 16);
        d2 += __shfl_down(d2, o, 16); d3 += __shfl_down(d3, o, 16);
    }
    if ((c & 15) == 0) {
        a_src[(n0 + nb + 0) * HEADS + h] = s0;
        a_src[(n0 + nb + 1) * HEADS + h] = s1;
        a_src[(n0 + nb + 2) * HEADS + h] = s2;
        a_src[(n0 + nb + 3) * HEADS + h] = s3;
        a_dst[(n0 + nb + 0) * HEADS + h] = d0;
        a_dst[(n0 + nb + 1) * HEADS + h] = d1;
        a_dst[(n0 + nb + 2) * HEADS + h] = d2;
        a_dst[(n0 + nb + 3) * HEADS + h] = d3;
    }
}

// ---------------- Layer 1: aggregate ----------------
// 1 wave per node (2 nodes / 128-block). Lane owns 2 bf16 channels (one dword gather).
// Single-exp online softmax; edge loop unrolled x4 for MLP.

__global__ __launch_bounds__(128) void l1_aggregate(
        const unsigned short* __restrict__ h1b, const float* __restrict__ a_src,
        const float* __restrict__ a_dst, const int* __restrict__ row_start,
        const int* __restrict__ csr_src, const float* __restrict__ b1,
        float* __restrict__ h_act) {
    int w = threadIdx.x >> 6;
    int lane = threadIdx.x & 63;
    int n = blockIdx.x * 2 + w;
    int c0 = lane * 2;
    int h = lane >> 3;          // (2*lane)>>4
    int beg = row_start[n], end = row_start[n + 1];
    float adst = a_dst[n * HEADS + h];
    float m = -INFINITY, l = 0.f, accx = 0.f, accy = 0.f;

    auto update = [&](float e, uint32 u) {
        float vx = __uint_as_float(u << 16);
        float vy = __uint_as_float(u & 0xFFFF0000u);
        e += adst;
        e = fmaxf(e, NEG_SLOPE * e);          // leaky relu
        float nm = fmaxf(m, e);
        float d = e - m;                      // +inf on first iter
        float t = __expf(-fabsf(d));
        float sc = (d >= 0.f) ? t : 1.f;
        float p  = (d >= 0.f) ? 1.f : t;
        l = fmaf(l, sc, p);
        accx = fmaf(accx, sc, p * vx);
        accy = fmaf(accy, sc, p * vy);
        m = nm;
    };

    int j = beg;
    for (; j + 4 <= end; j += 4) {
        int s0 = csr_src[j + 0], s1 = csr_src[j + 1];
        int s2 = csr_src[j + 2], s3 = csr_src[j + 3];
        float e0 = a_src[s0 * HEADS + h];
        float e1 = a_src[s1 * HEADS + h];
        float e2 = a_src[s2 * HEADS + h];
        float e3 = a_src[s3 * HEADS + h];
        uint32 u0 = *(const uint32*)&h1b[(size_t)s0 * HID + c0];
        uint32 u1 = *(const uint32*)&h1b[(size_t)s1 * HID + c0];
        uint32 u2 = *(const uint32*)&h1b[(size_t)s2 * HID + c0];
        uint32 u3 = *(const uint32*)&h1b[(size_t)s3 * HID + c0];
        update(e0, u0); update(e1, u1); update(e2, u2); update(e3, u3);
    }
    for (; j < end; ++j) {
        int s = csr_src[j];
        float e = a_src[s * HEADS + h];
        uint32 u = *(const uint32*)&h1b[(size_t)s * HID + c0];
        update(e, u);
    }

    float inv = 1.f / (l + 1e-16f);
    float vx = accx * inv + b1[c0];
    float vy = accy * inv + b1[c0 + 1];
    vx = vx > 0.f ? vx : (__expf(vx) - 1.f);   // ELU
    vy = vy > 0.f ? vy : (__expf(vy) - 1.f);
    float2 o = make_float2(vx, vy);
    *(float2*)&h_act[(size_t)n * HID + c0] = o;
}

// ---------------- Layer 2: transform ----------------
// h2 written as bf16 (ushort[N][64]) for the gather in l2_aggregate.

__global__ __launch_bounds__(256) void l2_transform(
        const float* __restrict__ h_act, const float* __restrict__ W2,
        const float* __restrict__ as2, const float* __restrict__ ad2,
        unsigned short* __restrict__ h2b, float* __restrict__ a_src2, float* __restrict__ a_dst2) {
    int n0 = blockIdx.x * 8;
    int t = threadIdx.x;
    int c = t & 63;
    int g = t >> 6;          // 0..3 -> nodes g*2, g*2+1
    __shared__ float hs[8][HID];
    for (int i = t; i < 8 * HID; i += 256) {
        hs[i >> 7][i & 127] = h_act[(size_t)(n0 + (i >> 7)) * HID + (i & 127)];
    }
    __syncthreads();
    int nb = g * 2;
    float acc0 = 0.f, acc1 = 0.f;
    #pragma unroll 8
    for (int k = 0; k < HID; ++k) {
        float w = W2[k * OUT_DIM + c];
        acc0 = fmaf(hs[nb + 0][k], w, acc0);
        acc1 = fmaf(hs[nb + 1][k], w, acc1);
    }
    h2b[(size_t)(n0 + nb + 0) * OUT_DIM + c] = f2bf(acc0);
    h2b[(size_t)(n0 + nb + 1) * OUT_DIM + c] = f2bf(acc1);

    float ws = as2[c], wd = ad2[c];
    float s0 = acc0 * ws, s1 = acc1 * ws;
    float d0 = acc0 * wd, d1 = acc1 * wd;
    #pragma unroll
    for (int o = 32; o > 0; o >>= 1) {
        s0 += __shfl_down(s0, o, 64); s1 += __shfl_down(s1, o, 64);
        d0 += __shfl_down(d0, o, 64); d1 += __shfl_down(d1, o, 64);
    }
    if (c == 0) {
        a_src2[n0 + nb + 0] = s0; a_src2[n0 + nb + 1] = s1;
        a_dst2[n0 + nb + 0] = d0; a_dst2[n0 + nb + 1] = d1;
    }
}

// ---------------- Layer 2: aggregate + log_softmax ----------------
// 1 wave per node (2 nodes / 128-block). Lane owns 1 channel (bf16 gather).

__global__ __launch_bounds__(128) void l2_aggregate(
        const unsigned short* __restrict__ h2b, const float* __restrict__ a_src2,
        const float* __restrict__ a_dst2, const int* __restrict__ row_start,
        const int* __restrict__ csr_src, const float* __restrict__ b2,
        float* __restrict__ out) {
    int w = threadIdx.x >> 6;
    int lane = threadIdx.x & 63;
    int n = blockIdx.x * 2 + w;
    int beg = row_start[n], end = row_start[n + 1];
    float adst = a_dst2[n];
    float m = -INFINITY, l = 0.f, acc = 0.f;

    auto update = [&](float e, unsigned short us) {
        float v = __uint_as_float(((uint32)us) << 16);
        e += adst;
        e = fmaxf(e, NEG_SLOPE * e);
        float nm = fmaxf(m, e);
        float d = e - m;
        float t = __expf(-fabsf(d));
        float sc = (d >= 0.f) ? t : 1.f;
        float p  = (d >= 0.f) ? 1.f : t;
        l = fmaf(l, sc, p);
        acc = fmaf(acc, sc, p * v);
        m = nm;
    };

    int j = beg;
    for (; j + 4 <= end; j += 4) {
        int s0 = csr_src[j + 0], s1 = csr_src[j + 1];
        int s2 = csr_src[j + 2], s3 = csr_src[j + 3];
        float e0 = a_src2[s0], e1 = a_src2[s1];
        float e2 = a_src2[s2], e3 = a_src2[s3];
        unsigned short v0 = h2b[(size_t)s0 * OUT_DIM + lane];
        unsigned short v1 = h2b[(size_t)s1 * OUT_DIM + lane];
        unsigned short v2 = h2b[(size_t)s2 * OUT_DIM + lane];
        unsigned short v3 = h2b[(size_t)s3 * OUT_DIM + lane];
        update(e0, v0); update(e1, v1); update(e2, v2); update(e3, v3);
    }
    for (; j < end; ++j) {
        int s = csr_src[j];
        update(a_src2[s], h2b[(size_t)s * OUT_DIM + lane]);
    }

    float o = acc / (l + 1e-16f) + b2[lane];
    // log_softmax over 64 channels (one wave)
    float mx = o;
    #pragma unroll
    for (int ww = 32; ww > 0; ww >>= 1) mx = fmaxf(mx, __shfl_xor(mx, ww, 64));
    float ex = __expf(o - mx);
    float ssum = ex;
    #pragma unroll
    for (int ww = 32; ww > 0; ww >>= 1) ssum += __shfl_xor(ssum, ww, 64);
    out[(size_t)n * OUT_DIM + lane] = o - mx - __logf(ssum);
}

// ---------------- launch ----------------

extern "C" void kernel_launch(void* const* d_in, const int* in_sizes, int n_in,
                              void* d_out, int out_size, void* d_ws, size_t ws_size,
                              hipStream_t stream) {
    const float* x   = (const float*)d_in[0];
    const int*   ei  = (const int*)d_in[1];
    const float* W1  = (const float*)d_in[2];
    const float* as1 = (const float*)d_in[3];
    const float* ad1 = (const float*)d_in[4];
    const float* b1  = (const float*)d_in[5];
    const float* W2  = (const float*)d_in[6];
    const float* as2 = (const float*)d_in[7];
    const float* ad2 = (const float*)d_in[8];
    const float* b2  = (const float*)d_in[9];
    float* out = (float*)d_out;

    const int* src = ei;             // row 0
    const int* dst = ei + E_EDGES;   // row 1

    char* ws = (char*)d_ws;
    size_t off = 0;
    auto alloc = [&](size_t bytes) -> void* {
        void* p = ws + off;
        off += (bytes + 255) & ~size_t(255);
        return p;
    };
    unsigned short* h1b = (unsigned short*)alloc((size_t)N_NODES * HID * 2);
    float* h_act        = (float*)alloc((size_t)N_NODES * HID * 4);
    unsigned short* h2b = (unsigned short*)alloc((size_t)N_NODES * OUT_DIM * 2);
    float* a_src1    = (float*)alloc((size_t)N_NODES * HEADS * 4);
    float* a_dst1    = (float*)alloc((size_t)N_NODES * HEADS * 4);
    float* a_src2    = (float*)alloc((size_t)N_NODES * 4);
    float* a_dst2    = (float*)alloc((size_t)N_NODES * 4);
    int*   row_start = (int*)alloc((size_t)(N_NODES + 1) * 4);
    int*   csr_src   = (int*)alloc((size_t)ET * 4);
    int2*  pairs     = (int2*)alloc((size_t)ET * 8);
    int*   cnt       = (int*)alloc((size_t)NB * NT * 4);
    int*   tileOff   = (int*)alloc((size_t)NB * NT * 4);
    int*   bucketStart = (int*)alloc((size_t)(NB + 1) * 4);

    bucket_hist<<<NT, 256, 0, stream>>>(dst, cnt);
    bucket_scan<<<1, 256, 0, stream>>>(cnt, tileOff, bucketStart);
    bucket_scatter<<<NT, 256, 0, stream>>>(src, dst, tileOff, bucketStart, pairs);
    bucket_build<<<NB, 256, 0, stream>>>(pairs, bucketStart, row_start, csr_src);

    l1_transform<<<N_NODES / 8, 256, 0, stream>>>(x, W1, as1, ad1, h1b, a_src1, a_dst1);
    l1_aggregate<<<N_NODES / 2, 128, 0, stream>>>(h1b, a_src1, a_dst1, row_start, csr_src, b1, h_act);
    l2_transform<<<N_NODES / 8, 256, 0, stream>>>(h_act, W2, as2, ad2, h2b, a_src2, a_dst2);
    l2_aggregate<<<N_NODES / 2, 128, 0, stream>>>(h2b, a_src2, a_dst2, row_start, csr_src, b2, out);
}

// Round 5
// 272.487 us; speedup vs baseline: 1.5617x; 1.1144x over previous
//
#include <hip/hip_runtime.h>
#include <math.h>

#define N_NODES 50000
#define E_EDGES 800000
#define ET      (E_EDGES + N_NODES)   // edges + self loops
#define IN_DIM  128
#define HID     128
#define HEADS   8
#define C1      16
#define OUT_DIM 64
#define NEG_SLOPE 0.2f

#define TILE    8192
#define NT      ((ET + TILE - 1) / TILE)      // 104 tiles
#define NB      ((N_NODES + 255) / 256)       // 196 buckets of 256 nodes

typedef unsigned int uint32;
typedef __attribute__((ext_vector_type(8))) short bf16x8;
typedef __attribute__((ext_vector_type(4))) float f32x4;

#define XS_LD 136   // padded LDS leading dim (bank-safe, 16B-aligned rows)

static __device__ __forceinline__ unsigned short f2bf(float f) {
    uint32 u = __float_as_uint(f);
    u += 0x7FFFu + ((u >> 16) & 1u);   // round to nearest even
    return (unsigned short)(u >> 16);
}

// ---------------- CSR build: two-level bucket sort, no global atomics ----------------

__global__ __launch_bounds__(256) void bucket_hist(
        const int* __restrict__ dst, int* __restrict__ cnt /* [NB][NT] */) {
    __shared__ int hist[NB];
    int t = threadIdx.x;
    for (int b = t; b < NB; b += 256) hist[b] = 0;
    __syncthreads();
    int base = blockIdx.x * TILE;
    #pragma unroll
    for (int it = 0; it < TILE / 256; ++it) {
        int i = base + it * 256 + t;
        if (i < ET) {
            int d = (i < E_EDGES) ? dst[i] : (i - E_EDGES);
            atomicAdd(&hist[d >> 8], 1);
        }
    }
    __syncthreads();
    for (int b = t; b < NB; b += 256) cnt[b * NT + blockIdx.x] = hist[b];
}

__global__ __launch_bounds__(256) void bucket_scan(
        const int* __restrict__ cnt, int* __restrict__ tileOff /* [NB][NT] */,
        int* __restrict__ bucketStart /* [NB+1] */) {
    __shared__ int s[256];
    int t = threadIdx.x;
    int total = 0;
    if (t < NB) {
        int run = 0;
        for (int k = 0; k < NT; ++k) {
            int c = cnt[t * NT + k];
            tileOff[t * NT + k] = run;
            run += c;
        }
        total = run;
    }
    s[t] = total;
    __syncthreads();
    #pragma unroll
    for (int off = 1; off < 256; off <<= 1) {
        int add = (t >= off) ? s[t - off] : 0;
        __syncthreads();
        s[t] += add;
        __syncthreads();
    }
    if (t < NB) bucketStart[t] = s[t] - total;   // exclusive
    if (t == 0) bucketStart[NB] = ET;
}

__global__ __launch_bounds__(256) void bucket_scatter(
        const int* __restrict__ src, const int* __restrict__ dst,
        const int* __restrict__ tileOff, const int* __restrict__ bucketStart,
        int2* __restrict__ pairs) {
    __shared__ int cur[NB];
    int t = threadIdx.x;
    for (int b = t; b < NB; b += 256)
        cur[b] = bucketStart[b] + tileOff[b * NT + blockIdx.x];
    __syncthreads();
    int base = blockIdx.x * TILE;
    #pragma unroll
    for (int it = 0; it < TILE / 256; ++it) {
        int i = base + it * 256 + t;
        if (i < ET) {
            int s, d;
            if (i < E_EDGES) { s = src[i]; d = dst[i]; }
            else             { s = d = i - E_EDGES; }
            int pos = atomicAdd(&cur[d >> 8], 1);
            pairs[pos] = make_int2(s, d);
        }
    }
}

__global__ __launch_bounds__(256) void bucket_build(
        const int2* __restrict__ pairs, const int* __restrict__ bucketStart,
        int* __restrict__ row_start, int* __restrict__ csr_src) {
    __shared__ int sdeg[256];
    __shared__ int sscan[256];
    int t = threadIdx.x;
    int b = blockIdx.x;
    int beg = bucketStart[b], end = bucketStart[b + 1];
    sdeg[t] = 0;
    __syncthreads();
    for (int j = beg + t; j < end; j += 256)
        atomicAdd(&sdeg[pairs[j].y & 255], 1);
    __syncthreads();
    int v = sdeg[t];
    sscan[t] = v;
    __syncthreads();
    #pragma unroll
    for (int off = 1; off < 256; off <<= 1) {
        int add = (t >= off) ? sscan[t - off] : 0;
        __syncthreads();
        sscan[t] += add;
        __syncthreads();
    }
    int pos0 = beg + sscan[t] - v;   // exclusive prefix within bucket
    int n = b * 256 + t;
    if (n < N_NODES) row_start[n] = pos0;
    if (b == 0 && t == 0) row_start[N_NODES] = ET;
    __syncthreads();
    sscan[t] = pos0;                 // reuse as cursor
    __syncthreads();
    for (int j = beg + t; j < end; j += 256) {
        int2 p = pairs[j];
        int pos = atomicAdd(&sscan[p.y & 255], 1);
        csr_src[pos] = p.x;
    }
}

// ---------------- Layer 1: transform via MFMA (bf16) ----------------
// Block = 256 thr = 4 waves; block covers 64 nodes (wave w: 16 nodes).
// A-frag: A[m=lane&15][k=quad*8+j]; B from transposed LDS wt[n][k];
// C/D: col=lane&15 (channel), row=quad*4+reg (node). Head == n-tile index.

__global__ __launch_bounds__(256) void l1_transform_mfma(
        const float* __restrict__ x, const float* __restrict__ W1,
        const float* __restrict__ as1, const float* __restrict__ ad1,
        unsigned short* __restrict__ h1b, float* __restrict__ a_src,
        float* __restrict__ a_dst) {
    __shared__ unsigned short xs[64][XS_LD];    // x-tile bf16
    __shared__ unsigned short wt[128][XS_LD];   // wt[n][k] = W1[k][n] bf16
    int t = threadIdx.x;
    int n0 = blockIdx.x * 64;
    for (int i = t; i < 64 * 128; i += 256) {
        int n = i >> 7, c = i & 127;
        int gn = n0 + n;
        float v = (gn < N_NODES) ? x[(size_t)gn * IN_DIM + c] : 0.f;
        xs[n][c] = f2bf(v);
    }
    for (int i = t; i < 128 * 128; i += 256) {
        int k = i >> 7, n = i & 127;
        wt[n][k] = f2bf(W1[i]);
    }
    __syncthreads();

    int w = t >> 6, lane = t & 63;
    int l15 = lane & 15, quad = lane >> 4;

    bf16x8 af[4];
    #pragma unroll
    for (int s = 0; s < 4; ++s)
        af[s] = *(const bf16x8*)&xs[w * 16 + l15][s * 32 + quad * 8];

    #pragma unroll
    for (int tt = 0; tt < 8; ++tt) {          // n-tile == head tt
        f32x4 acc = {0.f, 0.f, 0.f, 0.f};
        #pragma unroll
        for (int s = 0; s < 4; ++s) {
            bf16x8 bf = *(const bf16x8*)&wt[tt * 16 + l15][s * 32 + quad * 8];
            acc = __builtin_amdgcn_mfma_f32_16x16x32_bf16(af[s], bf, acc, 0, 0, 0);
        }
        int ch = tt * 16 + l15;
        float aS = as1[ch], aD = ad1[ch];
        #pragma unroll
        for (int r = 0; r < 4; ++r) {
            int node = n0 + w * 16 + quad * 4 + r;
            if (node < N_NODES)
                h1b[(size_t)node * HID + ch] = f2bf(acc[r]);
            float ps = acc[r] * aS, pd = acc[r] * aD;
            #pragma unroll
            for (int o = 1; o < 16; o <<= 1) {
                ps += __shfl_xor(ps, o, 16);
                pd += __shfl_xor(pd, o, 16);
            }
            if (l15 == 0 && node < N_NODES) {
                a_src[node * HEADS + tt] = ps;
                a_dst[node * HEADS + tt] = pd;
            }
        }
    }
}

// ---------------- Layer 1: aggregate (no-max softmax, bf16 out) ----------------

__global__ __launch_bounds__(128) void l1_aggregate(
        const unsigned short* __restrict__ h1b, const float* __restrict__ a_src,
        const float* __restrict__ a_dst, const int* __restrict__ row_start,
        const int* __restrict__ csr_src, const float* __restrict__ b1,
        unsigned short* __restrict__ h_act_b) {
    int w = threadIdx.x >> 6;
    int lane = threadIdx.x & 63;
    int n = blockIdx.x * 2 + w;
    int c0 = lane * 2;
    int h = lane >> 3;
    int beg = row_start[n], end = row_start[n + 1];
    float adst = a_dst[n * HEADS + h];
    float l = 0.f, accx = 0.f, accy = 0.f;

    auto update = [&](float e, uint32 u) {
        float vx = __uint_as_float(u << 16);
        float vy = __uint_as_float(u & 0xFFFF0000u);
        e += adst;
        e = fmaxf(e, NEG_SLOPE * e);          // leaky relu; |e| small -> exp safe
        float p = __expf(e);
        l += p;
        accx = fmaf(p, vx, accx);
        accy = fmaf(p, vy, accy);
    };

    int j = beg;
    for (; j + 4 <= end; j += 4) {
        int s0 = csr_src[j + 0], s1 = csr_src[j + 1];
        int s2 = csr_src[j + 2], s3 = csr_src[j + 3];
        float e0 = a_src[s0 * HEADS + h];
        float e1 = a_src[s1 * HEADS + h];
        float e2 = a_src[s2 * HEADS + h];
        float e3 = a_src[s3 * HEADS + h];
        uint32 u0 = *(const uint32*)&h1b[(size_t)s0 * HID + c0];
        uint32 u1 = *(const uint32*)&h1b[(size_t)s1 * HID + c0];
        uint32 u2 = *(const uint32*)&h1b[(size_t)s2 * HID + c0];
        uint32 u3 = *(const uint32*)&h1b[(size_t)s3 * HID + c0];
        update(e0, u0); update(e1, u1); update(e2, u2); update(e3, u3);
    }
    for (; j < end; ++j) {
        int s = csr_src[j];
        float e = a_src[s * HEADS + h];
        uint32 u = *(const uint32*)&h1b[(size_t)s * HID + c0];
        update(e, u);
    }

    float inv = 1.f / (l + 1e-16f);
    float vx = accx * inv + b1[c0];
    float vy = accy * inv + b1[c0 + 1];
    vx = vx > 0.f ? vx : (__expf(vx) - 1.f);   // ELU
    vy = vy > 0.f ? vy : (__expf(vy) - 1.f);
    uint32 packed = (uint32)f2bf(vx) | ((uint32)f2bf(vy) << 16);
    *(uint32*)&h_act_b[(size_t)n * HID + c0] = packed;
}

// ---------------- Layer 2: transform via MFMA (bf16) ----------------
// 64 nodes/block, N=64 (4 n-tiles), K=128 (4 k-steps). Single head.

__global__ __launch_bounds__(256) void l2_transform_mfma(
        const unsigned short* __restrict__ h_act_b, const float* __restrict__ W2,
        const float* __restrict__ as2, const float* __restrict__ ad2,
        unsigned short* __restrict__ h2b, float* __restrict__ a_src2,
        float* __restrict__ a_dst2) {
    __shared__ unsigned short hs[64][XS_LD];
    __shared__ unsigned short wt[64][XS_LD];   // wt[n][k] = W2[k][n] bf16
    int t = threadIdx.x;
    int n0 = blockIdx.x * 64;
    for (int i = t; i < 64 * 128; i += 256) {
        int n = i >> 7, c = i & 127;
        int gn = n0 + n;
        hs[n][c] = (gn < N_NODES) ? h_act_b[(size_t)gn * HID + c] : 0;
    }
    for (int i = t; i < 128 * 64; i += 256) {
        int k = i >> 6, n = i & 63;
        wt[n][k] = f2bf(W2[i]);
    }
    __syncthreads();

    int w = t >> 6, lane = t & 63;
    int l15 = lane & 15, quad = lane >> 4;

    bf16x8 af[4];
    #pragma unroll
    for (int s = 0; s < 4; ++s)
        af[s] = *(const bf16x8*)&hs[w * 16 + l15][s * 32 + quad * 8];

    float sS[4] = {0.f, 0.f, 0.f, 0.f};
    float sD[4] = {0.f, 0.f, 0.f, 0.f};
    #pragma unroll
    for (int tt = 0; tt < 4; ++tt) {
        f32x4 acc = {0.f, 0.f, 0.f, 0.f};
        #pragma unroll
        for (int s = 0; s < 4; ++s) {
            bf16x8 bf = *(const bf16x8*)&wt[tt * 16 + l15][s * 32 + quad * 8];
            acc = __builtin_amdgcn_mfma_f32_16x16x32_bf16(af[s], bf, acc, 0, 0, 0);
        }
        int ch = tt * 16 + l15;
        float aS = as2[ch], aD = ad2[ch];
        #pragma unroll
        for (int r = 0; r < 4; ++r) {
            int node = n0 + w * 16 + quad * 4 + r;
            if (node < N_NODES)
                h2b[(size_t)node * OUT_DIM + ch] = f2bf(acc[r]);
            sS[r] = fmaf(acc[r], aS, sS[r]);
            sD[r] = fmaf(acc[r], aD, sD[r]);
        }
    }
    #pragma unroll
    for (int r = 0; r < 4; ++r) {
        float ps = sS[r], pd = sD[r];
        #pragma unroll
        for (int o = 1; o < 16; o <<= 1) {
            ps += __shfl_xor(ps, o, 16);
            pd += __shfl_xor(pd, o, 16);
        }
        int node = n0 + w * 16 + quad * 4 + r;
        if (l15 == 0 && node < N_NODES) {
            a_src2[node] = ps;
            a_dst2[node] = pd;
        }
    }
}

// ---------------- Layer 2: aggregate + log_softmax ----------------

__global__ __launch_bounds__(128) void l2_aggregate(
        const unsigned short* __restrict__ h2b, const float* __restrict__ a_src2,
        const float* __restrict__ a_dst2, const int* __restrict__ row_start,
        const int* __restrict__ csr_src, const float* __restrict__ b2,
        float* __restrict__ out) {
    int w = threadIdx.x >> 6;
    int lane = threadIdx.x & 63;
    int n = blockIdx.x * 2 + w;
    int beg = row_start[n], end = row_start[n + 1];
    float adst = a_dst2[n];
    float l = 0.f, acc = 0.f;

    auto update = [&](float e, unsigned short us) {
        float v = __uint_as_float(((uint32)us) << 16);
        e += adst;
        e = fmaxf(e, NEG_SLOPE * e);
        float p = __expf(e);
        l += p;
        acc = fmaf(p, v, acc);
    };

    int j = beg;
    for (; j + 4 <= end; j += 4) {
        int s0 = csr_src[j + 0], s1 = csr_src[j + 1];
        int s2 = csr_src[j + 2], s3 = csr_src[j + 3];
        float e0 = a_src2[s0], e1 = a_src2[s1];
        float e2 = a_src2[s2], e3 = a_src2[s3];
        unsigned short v0 = h2b[(size_t)s0 * OUT_DIM + lane];
        unsigned short v1 = h2b[(size_t)s1 * OUT_DIM + lane];
        unsigned short v2 = h2b[(size_t)s2 * OUT_DIM + lane];
        unsigned short v3 = h2b[(size_t)s3 * OUT_DIM + lane];
        update(e0, v0); update(e1, v1); update(e2, v2); update(e3, v3);
    }
    for (; j < end; ++j) {
        int s = csr_src[j];
        update(a_src2[s], h2b[(size_t)s * OUT_DIM + lane]);
    }

    float o = acc / (l + 1e-16f) + b2[lane];
    // log_softmax over 64 channels (one wave)
    float mx = o;
    #pragma unroll
    for (int ww = 32; ww > 0; ww >>= 1) mx = fmaxf(mx, __shfl_xor(mx, ww, 64));
    float ex = __expf(o - mx);
    float ssum = ex;
    #pragma unroll
    for (int ww = 32; ww > 0; ww >>= 1) ssum += __shfl_xor(ssum, ww, 64);
    out[(size_t)n * OUT_DIM + lane] = o - mx - __logf(ssum);
}

// ---------------- launch ----------------

extern "C" void kernel_launch(void* const* d_in, const int* in_sizes, int n_in,
                              void* d_out, int out_size, void* d_ws, size_t ws_size,
                              hipStream_t stream) {
    const float* x   = (const float*)d_in[0];
    const int*   ei  = (const int*)d_in[1];
    const float* W1  = (const float*)d_in[2];
    const float* as1 = (const float*)d_in[3];
    const float* ad1 = (const float*)d_in[4];
    const float* b1  = (const float*)d_in[5];
    const float* W2  = (const float*)d_in[6];
    const float* as2 = (const float*)d_in[7];
    const float* ad2 = (const float*)d_in[8];
    const float* b2  = (const float*)d_in[9];
    float* out = (float*)d_out;

    const int* src = ei;             // row 0
    const int* dst = ei + E_EDGES;   // row 1

    char* ws = (char*)d_ws;
    size_t off = 0;
    auto alloc = [&](size_t bytes) -> void* {
        void* p = ws + off;
        off += (bytes + 255) & ~size_t(255);
        return p;
    };
    unsigned short* h1b    = (unsigned short*)alloc((size_t)N_NODES * HID * 2);
    unsigned short* h_act_b= (unsigned short*)alloc((size_t)N_NODES * HID * 2);
    unsigned short* h2b    = (unsigned short*)alloc((size_t)N_NODES * OUT_DIM * 2);
    float* a_src1    = (float*)alloc((size_t)N_NODES * HEADS * 4);
    float* a_dst1    = (float*)alloc((size_t)N_NODES * HEADS * 4);
    float* a_src2    = (float*)alloc((size_t)N_NODES * 4);
    float* a_dst2    = (float*)alloc((size_t)N_NODES * 4);
    int*   row_start = (int*)alloc((size_t)(N_NODES + 1) * 4);
    int*   csr_src   = (int*)alloc((size_t)ET * 4);
    int2*  pairs     = (int2*)alloc((size_t)ET * 8);
    int*   cnt       = (int*)alloc((size_t)NB * NT * 4);
    int*   tileOff   = (int*)alloc((size_t)NB * NT * 4);
    int*   bucketStart = (int*)alloc((size_t)(NB + 1) * 4);

    bucket_hist<<<NT, 256, 0, stream>>>(dst, cnt);
    bucket_scan<<<1, 256, 0, stream>>>(cnt, tileOff, bucketStart);
    bucket_scatter<<<NT, 256, 0, stream>>>(src, dst, tileOff, bucketStart, pairs);
    bucket_build<<<NB, 256, 0, stream>>>(pairs, bucketStart, row_start, csr_src);

    int tb = (N_NODES + 63) / 64;   // 782
    l1_transform_mfma<<<tb, 256, 0, stream>>>(x, W1, as1, ad1, h1b, a_src1, a_dst1);
    l1_aggregate<<<N_NODES / 2, 128, 0, stream>>>(h1b, a_src1, a_dst1, row_start, csr_src, b1, h_act_b);
    l2_transform_mfma<<<tb, 256, 0, stream>>>(h_act_b, W2, as2, ad2, h2b, a_src2, a_dst2);
    l2_aggregate<<<N_NODES / 2, 128, 0, stream>>>(h2b, a_src2, a_dst2, row_start, csr_src, b2, out);
}